// Round 1
// baseline (65.170 us; speedup 1.0000x reference)
//
#include <hip/hip_runtime.h>

#define INP (128*128*64)   // 1048576
#define NB 8
#define NBLK1 4096         // K1 blocks: INP / 256

// ---------------------------------------------------------------------------
// K1: fused affine_grid + trilinear grid_sample (zeros padding, align_corners
// =False) for all 8 batches at one spatial voxel per thread; also accumulates
// the per-batch dot <x_reg[b,:], ln_weight> into per-block partials.
// ---------------------------------------------------------------------------
__global__ __launch_bounds__(256) void k_sample(
    const float* __restrict__ x,       // (8, INP) viewed as (8,128,128,64) z,y,x
    const int*   __restrict__ r_index, // (8,)
    const float* __restrict__ theta,   // (100,3,4)
    const float* __restrict__ lnw,     // (INP)
    float* __restrict__ x_reg,         // out[0 .. 8*INP)
    float* __restrict__ partial)       // ws: (8, NBLK1)
{
    const int i = blockIdx.x * 256 + threadIdx.x;   // spatial flat idx in [0,INP)
    const int w = i & 63;          // x / W dim (64)
    const int h = (i >> 6) & 127;  // y / H dim (128)
    const int d = i >> 13;         // z / D dim (128)

    // normalized coords, align_corners=False: (2k+1)/n - 1
    const float xs = fmaf((float)w, 1.f/32.f, 1.f/64.f  - 1.f);
    const float ys = fmaf((float)h, 1.f/64.f, 1.f/128.f - 1.f);
    const float zs = fmaf((float)d, 1.f/64.f, 1.f/128.f - 1.f);

    const float wt = lnw[i];
    float acc[NB];

    #pragma unroll
    for (int b = 0; b < NB; ++b) {
        const float* t = theta + r_index[b] * 12;   // uniform -> scalar loads
        const float gx = t[0]*xs + t[1]*ys + t[2]*zs + t[3];
        const float gy = t[4]*xs + t[5]*ys + t[6]*zs + t[7];
        const float gz = t[8]*xs + t[9]*ys + t[10]*zs + t[11];
        // unnormalize: ix = ((g+1)*S - 1)/2
        const float ix = fmaf(gx, 32.f, 31.5f);
        const float iy = fmaf(gy, 64.f, 63.5f);
        const float iz = fmaf(gz, 64.f, 63.5f);

        const float x0f = floorf(ix), y0f = floorf(iy), z0f = floorf(iz);
        const int   x0 = (int)x0f,  y0 = (int)y0f,  z0 = (int)z0f;
        const float tx = ix - x0f,  ty = iy - y0f,  tz = iz - z0f;

        const float* __restrict__ vb = x + (size_t)b * INP;
        float out = 0.f;
        #pragma unroll
        for (int dz = 0; dz < 2; ++dz) {
            const float wz = dz ? tz : 1.f - tz;
            const int   zc = z0 + dz;
            #pragma unroll
            for (int dy = 0; dy < 2; ++dy) {
                const float wy = dy ? ty : 1.f - ty;
                const int   yc = y0 + dy;
                #pragma unroll
                for (int dx = 0; dx < 2; ++dx) {
                    const float wx = dx ? tx : 1.f - tx;
                    const int   xc = x0 + dx;
                    const bool valid = ((unsigned)xc < 64u) &
                                       ((unsigned)yc < 128u) &
                                       ((unsigned)zc < 128u);
                    const int xcc = min(max(xc, 0), 63);
                    const int ycc = min(max(yc, 0), 127);
                    const int zcc = min(max(zc, 0), 127);
                    const float v = vb[(zcc << 13) + (ycc << 6) + xcc];
                    out += valid ? (wx * wy * wz) * v : 0.f;
                }
            }
        }
        x_reg[(size_t)b * INP + i] = out;
        acc[b] = out * wt;
    }

    // deterministic block reduction of acc[0..7]
    __shared__ float sm[4 * NB];
    const int lane = threadIdx.x & 63;
    const int wv   = threadIdx.x >> 6;
    #pragma unroll
    for (int b = 0; b < NB; ++b) {
        float v = acc[b];
        #pragma unroll
        for (int off = 32; off > 0; off >>= 1) v += __shfl_down(v, off, 64);
        if (lane == 0) sm[wv * NB + b] = v;
    }
    __syncthreads();
    if (threadIdx.x < NB) {
        const float s = sm[threadIdx.x] + sm[NB + threadIdx.x] +
                        sm[2*NB + threadIdx.x] + sm[3*NB + threadIdx.x];
        partial[threadIdx.x * NBLK1 + blockIdx.x] = s;
    }
}

// ---------------------------------------------------------------------------
// K2: reduce (8, NBLK1) partials -> s[8]
// ---------------------------------------------------------------------------
__global__ __launch_bounds__(256) void k_reduce(
    const float* __restrict__ partial, float* __restrict__ s)
{
    const int b = blockIdx.x;
    float v = 0.f;
    for (int t = threadIdx.x; t < NBLK1; t += 256) v += partial[b * NBLK1 + t];
    __shared__ float sm[4];
    const int lane = threadIdx.x & 63;
    const int wv   = threadIdx.x >> 6;
    #pragma unroll
    for (int off = 32; off > 0; off >>= 1) v += __shfl_down(v, off, 64);
    if (lane == 0) sm[wv] = v;
    __syncthreads();
    if (threadIdx.x == 0) s[b] = sm[0] + sm[1] + sm[2] + sm[3];
}

// ---------------------------------------------------------------------------
// K3: L[b,i] = s[b] * lnw[i], float4 vectorized
// ---------------------------------------------------------------------------
__global__ __launch_bounds__(256) void k_outer(
    const float* __restrict__ lnw, const float* __restrict__ s,
    float* __restrict__ L)
{
    const int i = blockIdx.x * 256 + threadIdx.x;   // over INP/4
    const float4 w4 = ((const float4*)lnw)[i];
    #pragma unroll
    for (int b = 0; b < NB; ++b) {
        const float sb = s[b];
        float4 o;
        o.x = sb * w4.x; o.y = sb * w4.y; o.z = sb * w4.z; o.w = sb * w4.w;
        ((float4*)(L + (size_t)b * INP))[i] = o;
    }
}

extern "C" void kernel_launch(void* const* d_in, const int* in_sizes, int n_in,
                              void* d_out, int out_size, void* d_ws, size_t ws_size,
                              hipStream_t stream) {
    const float* x       = (const float*)d_in[0];
    const int*   r_index = (const int*)d_in[1];
    const float* theta   = (const float*)d_in[2];
    const float* lnw     = (const float*)d_in[3];

    float* x_reg = (float*)d_out;                       // (8, INP)
    float* L     = (float*)d_out + (size_t)NB * INP;    // (8, INP)

    float* partial = (float*)d_ws;          // 8*4096 floats = 128 KB
    float* s       = partial + NB * NBLK1;  // 8 floats

    k_sample<<<NBLK1, 256, 0, stream>>>(x, r_index, theta, lnw, x_reg, partial);
    k_reduce<<<NB, 256, 0, stream>>>(partial, s);
    k_outer<<<INP / 4 / 256, 256, 0, stream>>>(lnw, s, L);
}

// Round 2
// 43.322 us; speedup vs baseline: 1.5043x; 1.5043x over previous
//
#include <hip/hip_runtime.h>

#define INP (128*128*64)   // 1048576
#define NB 8
#define NBLK1 4096         // K1 blocks: INP / 256

typedef __attribute__((ext_vector_type(4))) float f32x4;

// ---------------------------------------------------------------------------
// K1: fused affine_grid + trilinear grid_sample (zeros padding, align_corners
// =False) for all 8 batches at one spatial voxel per thread; also accumulates
// the per-batch dot <x_reg[b,:], ln_weight> into per-block partials.
// MLP-restructured: all 8 corner loads issued independently before use.
// ---------------------------------------------------------------------------
__global__ __launch_bounds__(256) void k_sample(
    const float* __restrict__ x,       // (8, INP) viewed as (8,128,128,64) z,y,x
    const int*   __restrict__ r_index, // (8,)
    const float* __restrict__ theta,   // (100,3,4)
    const float* __restrict__ lnw,     // (INP)
    float* __restrict__ x_reg,         // out[0 .. 8*INP)
    float* __restrict__ partial)       // ws: (8, NBLK1)
{
    const int i = blockIdx.x * 256 + threadIdx.x;   // spatial flat idx in [0,INP)
    const int w = i & 63;          // x / W dim (64)
    const int h = (i >> 6) & 127;  // y / H dim (128)
    const int d = i >> 13;         // z / D dim (128)

    // normalized coords, align_corners=False: (2k+1)/n - 1
    const float xs = fmaf((float)w, 1.f/32.f, 1.f/64.f  - 1.f);
    const float ys = fmaf((float)h, 1.f/64.f, 1.f/128.f - 1.f);
    const float zs = fmaf((float)d, 1.f/64.f, 1.f/128.f - 1.f);

    const float wt = lnw[i];
    float acc[NB];

    #pragma unroll
    for (int b = 0; b < NB; ++b) {
        const float* t = theta + r_index[b] * 12;   // uniform -> scalar loads
        float ix = fmaf(t[0], xs, fmaf(t[1], ys, fmaf(t[2],  zs, t[3])));
        float iy = fmaf(t[4], xs, fmaf(t[5], ys, fmaf(t[6],  zs, t[7])));
        float iz = fmaf(t[8], xs, fmaf(t[9], ys, fmaf(t[10], zs, t[11])));
        ix = fmaf(ix, 32.f, 31.5f);
        iy = fmaf(iy, 64.f, 63.5f);
        iz = fmaf(iz, 64.f, 63.5f);

        const float x0f = floorf(ix), y0f = floorf(iy), z0f = floorf(iz);
        const int   x0 = (int)x0f,  y0 = (int)y0f,  z0 = (int)z0f;
        const float tx = ix - x0f,  ty = iy - y0f,  tz = iz - z0f;

        // per-dimension weights, zeroed when that coordinate is out of range
        float wx1 = tx,        wx0 = 1.f - tx;
        float wy1 = ty,        wy0 = 1.f - ty;
        float wz1 = tz,        wz0 = 1.f - tz;
        wx0 = ((unsigned)x0       < 64u)  ? wx0 : 0.f;
        wx1 = ((unsigned)(x0 + 1) < 64u)  ? wx1 : 0.f;
        wy0 = ((unsigned)y0       < 128u) ? wy0 : 0.f;
        wy1 = ((unsigned)(y0 + 1) < 128u) ? wy1 : 0.f;
        wz0 = ((unsigned)z0       < 128u) ? wz0 : 0.f;
        wz1 = ((unsigned)(z0 + 1) < 128u) ? wz1 : 0.f;

        // clamped addresses (x-clamp independent of y/z)
        const int xc0 = min(max(x0,     0), 63);
        const int xc1 = min(max(x0 + 1, 0), 63);
        const int yc0 = min(max(y0,     0), 127);
        const int yc1 = min(max(y0 + 1, 0), 127);
        const int zc0 = min(max(z0,     0), 127);
        const int zc1 = min(max(z0 + 1, 0), 127);

        const int rb00 = (zc0 << 13) + (yc0 << 6);
        const int rb01 = (zc0 << 13) + (yc1 << 6);
        const int rb10 = (zc1 << 13) + (yc0 << 6);
        const int rb11 = (zc1 << 13) + (yc1 << 6);

        const float* __restrict__ vb = x + (size_t)b * INP;
        // 8 independent loads — keep them clustered for MLP
        const float v000 = vb[rb00 + xc0];
        const float v001 = vb[rb00 + xc1];
        const float v010 = vb[rb01 + xc0];
        const float v011 = vb[rb01 + xc1];
        const float v100 = vb[rb10 + xc0];
        const float v101 = vb[rb10 + xc1];
        const float v110 = vb[rb11 + xc0];
        const float v111 = vb[rb11 + xc1];

        const float wzy00 = wz0 * wy0;
        const float wzy01 = wz0 * wy1;
        const float wzy10 = wz1 * wy0;
        const float wzy11 = wz1 * wy1;

        float out;
        out  = v000 * (wzy00 * wx0);
        out  = fmaf(v001, wzy00 * wx1, out);
        out  = fmaf(v010, wzy01 * wx0, out);
        out  = fmaf(v011, wzy01 * wx1, out);
        out  = fmaf(v100, wzy10 * wx0, out);
        out  = fmaf(v101, wzy10 * wx1, out);
        out  = fmaf(v110, wzy11 * wx0, out);
        out  = fmaf(v111, wzy11 * wx1, out);

        __builtin_nontemporal_store(out, x_reg + (size_t)b * INP + i);
        acc[b] = out * wt;
    }

    // deterministic block reduction of acc[0..7]
    __shared__ float sm[4 * NB];
    const int lane = threadIdx.x & 63;
    const int wv   = threadIdx.x >> 6;
    #pragma unroll
    for (int b = 0; b < NB; ++b) {
        float v = acc[b];
        #pragma unroll
        for (int off = 32; off > 0; off >>= 1) v += __shfl_down(v, off, 64);
        if (lane == 0) sm[wv * NB + b] = v;
    }
    __syncthreads();
    if (threadIdx.x < NB) {
        const float s = sm[threadIdx.x] + sm[NB + threadIdx.x] +
                        sm[2*NB + threadIdx.x] + sm[3*NB + threadIdx.x];
        partial[threadIdx.x * NBLK1 + blockIdx.x] = s;
    }
}

// ---------------------------------------------------------------------------
// K2: reduce (8, NBLK1) partials -> s[8]
// ---------------------------------------------------------------------------
__global__ __launch_bounds__(256) void k_reduce(
    const float* __restrict__ partial, float* __restrict__ s)
{
    const int b = blockIdx.x;
    float v = 0.f;
    for (int t = threadIdx.x; t < NBLK1; t += 256) v += partial[b * NBLK1 + t];
    __shared__ float sm[4];
    const int lane = threadIdx.x & 63;
    const int wv   = threadIdx.x >> 6;
    #pragma unroll
    for (int off = 32; off > 0; off >>= 1) v += __shfl_down(v, off, 64);
    if (lane == 0) sm[wv] = v;
    __syncthreads();
    if (threadIdx.x == 0) s[b] = sm[0] + sm[1] + sm[2] + sm[3];
}

// ---------------------------------------------------------------------------
// K3: L[b,i] = s[b] * lnw[i], float4 vectorized, nontemporal stores
// ---------------------------------------------------------------------------
__global__ __launch_bounds__(256) void k_outer(
    const float* __restrict__ lnw, const float* __restrict__ s,
    float* __restrict__ L)
{
    const int i = blockIdx.x * 256 + threadIdx.x;   // over INP/4
    const f32x4 w4 = ((const f32x4*)lnw)[i];
    #pragma unroll
    for (int b = 0; b < NB; ++b) {
        const float sb = s[b];
        f32x4 o = sb * w4;
        __builtin_nontemporal_store(o, (f32x4*)(L + (size_t)b * INP) + i);
    }
}

extern "C" void kernel_launch(void* const* d_in, const int* in_sizes, int n_in,
                              void* d_out, int out_size, void* d_ws, size_t ws_size,
                              hipStream_t stream) {
    const float* x       = (const float*)d_in[0];
    const int*   r_index = (const int*)d_in[1];
    const float* theta   = (const float*)d_in[2];
    const float* lnw     = (const float*)d_in[3];

    float* x_reg = (float*)d_out;                       // (8, INP)
    float* L     = (float*)d_out + (size_t)NB * INP;    // (8, INP)

    float* partial = (float*)d_ws;          // 8*4096 floats = 128 KB
    float* s       = partial + NB * NBLK1;  // 8 floats

    k_sample<<<NBLK1, 256, 0, stream>>>(x, r_index, theta, lnw, x_reg, partial);
    k_reduce<<<NB, 256, 0, stream>>>(partial, s);
    k_outer<<<INP / 4 / 256, 256, 0, stream>>>(lnw, s, L);
}

// Round 4
// 43.020 us; speedup vs baseline: 1.5149x; 1.0070x over previous
//
#include <hip/hip_runtime.h>

#define INP (128*128*64)   // 1048576
#define NB 8
#define NBLK1 4096         // K1 blocks: INP / 256

typedef __attribute__((ext_vector_type(4))) float f32x4;
typedef int v4i __attribute__((ext_vector_type(4)));

// ---------------------------------------------------------------------------
// Buffer-resource loads: 32-bit voffset addressing (pure VALU saving).
// All offsets are clamped in-bounds by construction — no reliance on the
// hardware OOB path (that gamble failed in R3 at the negative-offset edge).
// ---------------------------------------------------------------------------
#if __has_builtin(__builtin_amdgcn_make_buffer_rsrc) && __has_builtin(__builtin_amdgcn_raw_buffer_load_b32)
#define RSRC_T __amdgpu_buffer_rsrc_t
__device__ __forceinline__ RSRC_T make_rsrc(const float* p) {
    return __builtin_amdgcn_make_buffer_rsrc((void*)p, (short)0, INP * 4, 0x00020000);
}
__device__ __forceinline__ float bload(RSRC_T r, int boff) {
    return __builtin_bit_cast(float, __builtin_amdgcn_raw_buffer_load_b32(r, boff, 0, 0));
}
#else
#define RSRC_T v4i
__device__ __forceinline__ RSRC_T make_rsrc(const float* p) {
    union { const float* p; unsigned u[2]; } pun; pun.p = p;
    RSRC_T r;
    r.x = (int)pun.u[0]; r.y = (int)pun.u[1]; r.z = INP * 4; r.w = 0x00020000;
    return r;
}
__device__ __forceinline__ float bload(RSRC_T r, int boff) {
    return __builtin_amdgcn_raw_buffer_load_f32(r, boff, 0, 0);
}
#endif

// per-batch sample prep: 8 in-bounds byte offsets + 6 zeroed axis weights
struct Smp {
    int o[8];
    float wx0, wx1, wy0, wy1, wz0, wz1;
};

__device__ __forceinline__ Smp prep(const float* __restrict__ t,
                                    float xs, float ys, float zs) {
    float ix = fmaf(t[0], xs, fmaf(t[1], ys, fmaf(t[2],  zs, t[3])));
    float iy = fmaf(t[4], xs, fmaf(t[5], ys, fmaf(t[6],  zs, t[7])));
    float iz = fmaf(t[8], xs, fmaf(t[9], ys, fmaf(t[10], zs, t[11])));
    ix = fmaf(ix, 32.f, 31.5f);
    iy = fmaf(iy, 64.f, 63.5f);
    iz = fmaf(iz, 64.f, 63.5f);

    const float fx = floorf(ix), fy = floorf(iy), fz = floorf(iz);
    const int x0 = (int)fx, y0 = (int)fy, z0 = (int)fz;
    const int x1 = x0 + 1,  y1 = y0 + 1,  z1 = z0 + 1;

    Smp s;
    s.wx1 = ix - fx; s.wx0 = 1.f - s.wx1;
    s.wy1 = iy - fy; s.wy0 = 1.f - s.wy1;
    s.wz1 = iz - fz; s.wz0 = 1.f - s.wz1;
    // zeros-padding: zero the axis weight of any out-of-range plane
    s.wx0 = ((unsigned)x0 < 64u)  ? s.wx0 : 0.f;
    s.wx1 = ((unsigned)x1 < 64u)  ? s.wx1 : 0.f;
    s.wy0 = ((unsigned)y0 < 128u) ? s.wy0 : 0.f;
    s.wy1 = ((unsigned)y1 < 128u) ? s.wy1 : 0.f;
    s.wz0 = ((unsigned)z0 < 128u) ? s.wz0 : 0.f;
    s.wz1 = ((unsigned)z1 < 128u) ? s.wz1 : 0.f;

    // clamped, always-in-bounds byte offsets (R2-proven semantics)
    const int xc0 = min(max(x0, 0), 63),  xc1 = min(max(x1, 0), 63);
    const int yc0 = min(max(y0, 0), 127), yc1 = min(max(y1, 0), 127);
    const int zc0 = min(max(z0, 0), 127), zc1 = min(max(z1, 0), 127);
    // byte row base = ((z*128 + y)*64 + x)*4 = ((z<<7)+y)<<8 | x<<2
    const int rb00 = ((zc0 << 7) + yc0) << 8;
    const int rb01 = ((zc0 << 7) + yc1) << 8;
    const int rb10 = ((zc1 << 7) + yc0) << 8;
    const int rb11 = ((zc1 << 7) + yc1) << 8;
    const int xb0 = xc0 << 2, xb1 = xc1 << 2;
    s.o[0] = rb00 + xb0; s.o[1] = rb00 + xb1;
    s.o[2] = rb01 + xb0; s.o[3] = rb01 + xb1;
    s.o[4] = rb10 + xb0; s.o[5] = rb10 + xb1;
    s.o[6] = rb11 + xb0; s.o[7] = rb11 + xb1;
    return s;
}

__device__ __forceinline__ float blend(const Smp& s, const float v[8]) {
    const float bx00 = fmaf(s.wx1, v[1], s.wx0 * v[0]);
    const float bx01 = fmaf(s.wx1, v[3], s.wx0 * v[2]);
    const float bx10 = fmaf(s.wx1, v[5], s.wx0 * v[4]);
    const float bx11 = fmaf(s.wx1, v[7], s.wx0 * v[6]);
    const float by0  = fmaf(s.wy1, bx01, s.wy0 * bx00);
    const float by1  = fmaf(s.wy1, bx11, s.wy0 * bx10);
    return fmaf(s.wz1, by1, s.wz0 * by0);
}

// ---------------------------------------------------------------------------
// K1: fused affine_grid + trilinear grid_sample, 8 batches per thread in two
// 4-batch phases: all 32 loads of a phase issued before any blend (MLP=32).
// __launch_bounds__(256,4): 128-VGPR budget so the scheduler keeps them in
// flight instead of serializing at 32 VGPR like R2.
// ---------------------------------------------------------------------------
__global__ __launch_bounds__(256, 4) void k_sample(
    const float* __restrict__ x,       // (8, INP) as (8,128,128,64) z,y,x
    const int*   __restrict__ r_index, // (8,)
    const float* __restrict__ theta,   // (100,3,4)
    const float* __restrict__ lnw,     // (INP)
    float* __restrict__ x_reg,         // out[0 .. 8*INP)
    float* __restrict__ partial)       // ws: (8, NBLK1)
{
    const int i = blockIdx.x * 256 + threadIdx.x;
    const int w = i & 63;
    const int h = (i >> 6) & 127;
    const int d = i >> 13;

    const float xs = fmaf((float)w, 1.f/32.f, 1.f/64.f  - 1.f);
    const float ys = fmaf((float)h, 1.f/64.f, 1.f/128.f - 1.f);
    const float zs = fmaf((float)d, 1.f/64.f, 1.f/128.f - 1.f);

    const float wt = lnw[i];
    float acc[NB];

    #pragma unroll
    for (int half = 0; half < 2; ++half) {
        const int b0 = half * 4;
        Smp    s[4];
        RSRC_T r[4];
        #pragma unroll
        for (int k = 0; k < 4; ++k) {
            s[k] = prep(theta + r_index[b0 + k] * 12, xs, ys, zs);
            r[k] = make_rsrc(x + (size_t)(b0 + k) * INP);
        }
        float v[4][8];
        #pragma unroll
        for (int k = 0; k < 4; ++k)
            #pragma unroll
            for (int j = 0; j < 8; ++j)
                v[k][j] = bload(r[k], s[k].o[j]);
        #pragma unroll
        for (int k = 0; k < 4; ++k) {
            const float out = blend(s[k], v[k]);
            __builtin_nontemporal_store(out, x_reg + (size_t)(b0 + k) * INP + i);
            acc[b0 + k] = out * wt;
        }
    }

    // deterministic block reduction of acc[0..7]
    __shared__ float sm[4 * NB];
    const int lane = threadIdx.x & 63;
    const int wv   = threadIdx.x >> 6;
    #pragma unroll
    for (int b = 0; b < NB; ++b) {
        float v = acc[b];
        #pragma unroll
        for (int off = 32; off > 0; off >>= 1) v += __shfl_down(v, off, 64);
        if (lane == 0) sm[wv * NB + b] = v;
    }
    __syncthreads();
    if (threadIdx.x < NB) {
        const float s = sm[threadIdx.x] + sm[NB + threadIdx.x] +
                        sm[2*NB + threadIdx.x] + sm[3*NB + threadIdx.x];
        partial[threadIdx.x * NBLK1 + blockIdx.x] = s;
    }
}

// ---------------------------------------------------------------------------
// K2: reduce (8, NBLK1) partials -> s[8]
// ---------------------------------------------------------------------------
__global__ __launch_bounds__(256) void k_reduce(
    const float* __restrict__ partial, float* __restrict__ s)
{
    const int b = blockIdx.x;
    float v = 0.f;
    for (int t = threadIdx.x; t < NBLK1; t += 256) v += partial[b * NBLK1 + t];
    __shared__ float sm[4];
    const int lane = threadIdx.x & 63;
    const int wv   = threadIdx.x >> 6;
    #pragma unroll
    for (int off = 32; off > 0; off >>= 1) v += __shfl_down(v, off, 64);
    if (lane == 0) sm[wv] = v;
    __syncthreads();
    if (threadIdx.x == 0) s[b] = sm[0] + sm[1] + sm[2] + sm[3];
}

// ---------------------------------------------------------------------------
// K3: L[b,i] = s[b] * lnw[i], float4 vectorized, nontemporal stores
// ---------------------------------------------------------------------------
__global__ __launch_bounds__(256) void k_outer(
    const float* __restrict__ lnw, const float* __restrict__ s,
    float* __restrict__ L)
{
    const int i = blockIdx.x * 256 + threadIdx.x;   // over INP/4
    const f32x4 w4 = ((const f32x4*)lnw)[i];
    #pragma unroll
    for (int b = 0; b < NB; ++b) {
        const float sb = s[b];
        f32x4 o = sb * w4;
        __builtin_nontemporal_store(o, (f32x4*)(L + (size_t)b * INP) + i);
    }
}

extern "C" void kernel_launch(void* const* d_in, const int* in_sizes, int n_in,
                              void* d_out, int out_size, void* d_ws, size_t ws_size,
                              hipStream_t stream) {
    const float* x       = (const float*)d_in[0];
    const int*   r_index = (const int*)d_in[1];
    const float* theta   = (const float*)d_in[2];
    const float* lnw     = (const float*)d_in[3];

    float* x_reg = (float*)d_out;                       // (8, INP)
    float* L     = (float*)d_out + (size_t)NB * INP;    // (8, INP)

    float* partial = (float*)d_ws;          // 8*4096 floats = 128 KB
    float* s       = partial + NB * NBLK1;  // 8 floats

    k_sample<<<NBLK1, 256, 0, stream>>>(x, r_index, theta, lnw, x_reg, partial);
    k_reduce<<<NB, 256, 0, stream>>>(partial, s);
    k_outer<<<INP / 4 / 256, 256, 0, stream>>>(lnw, s, L);
}